// Round 3
// baseline (327.725 us; speedup 1.0000x reference)
//
#include <hip/hip_runtime.h>
#include <hip/hip_bf16.h>

// SelfAttentionLayer: B=64 S=512 E=512 H=8 D=64
// Round 3: K/V-once attention. Block = (b,h), 512 threads, 8 waves.
//   - Q A-frags held in registers for all 32 query-strips (16 q each)
//   - K/V streamed in 64-key chunks through 16 KB of swizzled LDS via
//     global_load_lds; each chunk consumed by all strips -> K/V HBM-fetched once
//   - softmax in exp2 domain: Q pre-scaled by log2(e)/sqrt(E) in qkv epilogue,
//     mask folded as -1.4427e10 * mask; p = v_exp_f32 directly
//   - O accumulated in AGPRs (4 strips x 4 n-tiles f4v), single deferred
//     l-normalization
// qkv_gemm / outproj: unchanged 128x128 async-swizzled MFMA GEMMs (round 2).

#define Bn 64
#define Sn 512
#define En 512
#define Hn 8
#define Dn 64

typedef __attribute__((ext_vector_type(8))) short s8v;   // 8 bf16 = 4 VGPRs
typedef __attribute__((ext_vector_type(4))) float f4v;   // 4 fp32 acc

__device__ __forceinline__ unsigned short f2bf(float f) {
    union { float f; unsigned int u; } v; v.f = f;
    unsigned int u = v.u;
    u += 0x7fffu + ((u >> 16) & 1u);   // round-to-nearest-even
    return (unsigned short)(u >> 16);
}

__device__ __forceinline__ void async16(const unsigned short* g, unsigned short* l) {
    __builtin_amdgcn_global_load_lds((const __attribute__((address_space(1))) void*)g,
                                     (__attribute__((address_space(3))) void*)l, 16, 0, 0);
}
__device__ __forceinline__ void async4(const float* g, float* l) {
    __builtin_amdgcn_global_load_lds((const __attribute__((address_space(1))) void*)g,
                                     (__attribute__((address_space(3))) void*)l, 4, 0, 0);
}

// ---------------------------------------------------------------- prep_h
__global__ __launch_bounds__(256) void prep_h(const float* __restrict__ x,
                                              const float* __restrict__ BE,
                                              unsigned short* __restrict__ hbf) {
    int i = (blockIdx.x * 256 + threadIdx.x) * 4;
    int se = i % (Sn * En);
    float4 a = *(const float4*)(x + i);
    float4 b = *(const float4*)(BE + se);
    ushort4 o;
    o.x = f2bf(a.x + b.x); o.y = f2bf(a.y + b.y);
    o.z = f2bf(a.z + b.z); o.w = f2bf(a.w + b.w);
    *(ushort4*)(hbf + i) = o;
}

// ---------------------------------------------------------------- prep_w
__global__ __launch_bounds__(256) void prep_w(const float* __restrict__ WQ,
                                              const float* __restrict__ WK,
                                              const float* __restrict__ WV,
                                              const float* __restrict__ WO,
                                              unsigned short* __restrict__ Wqkvt,
                                              unsigned short* __restrict__ WOt) {
    int idx = blockIdx.x * 256 + threadIdx.x;
    const int NW = 3 * Hn * Dn * En;                   // 786432
    if (idx < NW) {
        int e = idx & 511;
        int d = (idx >> 9) & 63;
        int h = (idx >> 15) & 7;
        int m = idx >> 18;
        const float* W = (m == 0) ? WQ : (m == 1) ? WK : WV;
        Wqkvt[idx] = f2bf(W[(h * En + e) * Dn + d]);   // [m][h][d][e]
    } else {
        int j = idx - NW;
        int n = j & 511;
        int e = j >> 9;
        WOt[j] = f2bf(WO[n * En + e]);                  // WO_t[e][hd]
    }
}

// ---------------------------------------------------------------- qkv_gemm
// C[32768,1536] = hbf[32768,512] x Wqkvt^T. grid (12 nb, 256 mb), 256 thr.
__global__ __launch_bounds__(256) void qkv_gemm(const unsigned short* __restrict__ hbf,
                                                const unsigned short* __restrict__ Wqkvt,
                                                unsigned short* __restrict__ Qo,
                                                unsigned short* __restrict__ Ko,
                                                unsigned short* __restrict__ Vt) {
    int nb = blockIdx.x, mb = blockIdx.y;
    __shared__ __align__(16) unsigned short At[128 * 64];
    __shared__ __align__(16) unsigned short Bt[128 * 64];
    int tid = threadIdx.x;
    int w = tid >> 6, lane = tid & 63, quad = lane >> 4, l16 = lane & 15;
    int wr = w >> 1, wc = w & 1;
    int lrow = lane >> 3;
    int lseg = ((lane & 7) ^ lrow) * 8;

    f4v acc[4][4];
#pragma unroll
    for (int i = 0; i < 4; i++)
#pragma unroll
        for (int n = 0; n < 4; n++) acc[i][n] = (f4v){0.f, 0.f, 0.f, 0.f};

    const unsigned short* Ag = hbf + (size_t)mb * 128 * 512;
    const unsigned short* Bg = Wqkvt + (size_t)nb * 128 * 512;

    for (int kc = 0; kc < 8; kc++) {
        __syncthreads();
#pragma unroll
        for (int i = 0; i < 4; i++) {
            int r0 = w * 32 + i * 8;
            async16(Ag + (r0 + lrow) * 512 + kc * 64 + lseg, &At[r0 * 64]);
            async16(Bg + (r0 + lrow) * 512 + kc * 64 + lseg, &Bt[r0 * 64]);
        }
        __syncthreads();
#pragma unroll
        for (int ks = 0; ks < 2; ks++) {
            int sw = ((ks * 4 + quad) ^ (l16 & 7)) * 8;
            s8v a[4], b[4];
#pragma unroll
            for (int i = 0; i < 4; i++)
                a[i] = *(const s8v*)&At[(wr * 64 + i * 16 + l16) * 64 + sw];
#pragma unroll
            for (int n = 0; n < 4; n++)
                b[n] = *(const s8v*)&Bt[(wc * 64 + n * 16 + l16) * 64 + sw];
#pragma unroll
            for (int i = 0; i < 4; i++)
#pragma unroll
                for (int n = 0; n < 4; n++)
                    acc[i][n] = __builtin_amdgcn_mfma_f32_16x16x32_bf16(a[i], b[n], acc[i][n], 0, 0, 0);
        }
    }

    int mat = nb >> 2;
    int h = (nb & 3) * 2 + wc;
    int b = mb >> 2;
    int s0 = (mb & 3) * 128 + wr * 64;
    // log2(e)/sqrt(512): folds both score scale and exp->exp2 conversion into Q
    const float qscale = 0.06375873f;

    if (mat < 2) {
        unsigned short* op = (mat == 0) ? Qo : Ko;
        float sc = (mat == 0) ? qscale : 1.0f;
#pragma unroll
        for (int i = 0; i < 4; i++)
#pragma unroll
            for (int n = 0; n < 4; n++)
#pragma unroll
                for (int r = 0; r < 4; r++) {
                    int s = s0 + i * 16 + quad * 4 + r;
                    int d = n * 16 + l16;
                    op[(size_t)((b * Hn + h) * Sn + s) * Dn + d] = f2bf(acc[i][n][r] * sc);
                }
    } else {
        // V transposed: Vt[b][h][d][s]
#pragma unroll
        for (int i = 0; i < 4; i++)
#pragma unroll
            for (int n = 0; n < 4; n++) {
                int d = n * 16 + l16;
                int s = s0 + i * 16 + quad * 4;
                ushort4 pk;
                pk.x = f2bf(acc[i][n][0]); pk.y = f2bf(acc[i][n][1]);
                pk.z = f2bf(acc[i][n][2]); pk.w = f2bf(acc[i][n][3]);
                *(ushort4*)&Vt[(size_t)((b * Hn + h) * Dn + d) * Sn + s] = pk;
            }
    }
}

// ---------------------------------------------------------------- attention
// Block = (b,h), 512 threads (8 waves). Wave w owns strips t = w*4+i (i<4),
// strip t = queries [t*16, t*16+16). K/V chunked 64 keys at a time; each
// chunk fetched from HBM exactly once per (b,h).
__global__ __launch_bounds__(512) void attn_kernel(const unsigned short* __restrict__ Q,
                                                   const unsigned short* __restrict__ K,
                                                   const unsigned short* __restrict__ Vt,
                                                   const float* __restrict__ mask,
                                                   unsigned short* __restrict__ attn) {
    int bh = blockIdx.x;
    int h = bh & 7, b = bh >> 3;
    __shared__ __align__(16) unsigned short Kc[64 * 64];    // [key][d] swizzled
    __shared__ __align__(16) unsigned short Vc[64 * 64];    // [d][key] swizzled
    __shared__ __align__(16) unsigned short Ps[8][16 * 64]; // wave-private P
    __shared__ float maskv[64];
    int tid = threadIdx.x;
    int w = tid >> 6, lane = tid & 63, quad = lane >> 4, l16 = lane & 15;
    int l7 = l16 & 7, lh = l16 >> 3;
    int q4 = (quad & 1) * 4;

    const unsigned short* Qg = Q + (size_t)(bh * Sn) * Dn;
    const unsigned short* Kg = K + (size_t)(bh * Sn) * Dn;
    const unsigned short* Vg = Vt + (size_t)(bh * Dn) * Sn;

    // Q A-frags for my 4 strips, held in registers the whole kernel
    s8v aq[4][2];
#pragma unroll
    for (int i = 0; i < 4; i++)
#pragma unroll
        for (int ks = 0; ks < 2; ks++)
            aq[i][ks] = *(const s8v*)&Qg[((w * 4 + i) * 16 + l16) * 64 + ks * 32 + quad * 8];

    f4v acc[4][4];
    float psum[4][4];
#pragma unroll
    for (int i = 0; i < 4; i++)
#pragma unroll
        for (int n = 0; n < 4; n++) {
            acc[i][n] = (f4v){0.f, 0.f, 0.f, 0.f};
            psum[i][n] = 0.f;   // reuse [i][r] indexing below
        }

    // staging geometry: wave w stages rows w*8 + (lane>>3), seg' = lane&7
    int srow = w * 8 + (lane >> 3);
    int sseg = ((lane & 7) ^ (srow & 7)) * 8;
    unsigned short* kdst = &Kc[w * 512];
    unsigned short* vdst = &Vc[w * 512];

    for (int kc = 0; kc < 8; kc++) {
        __syncthreads();                           // all waves done with prev chunk
        async16(Kg + (kc * 64 + srow) * 64 + sseg, kdst);
        async16(Vg + srow * 512 + kc * 64 + sseg, vdst);
        if (w == 0) async4(mask + b * Sn + kc * 64 + lane, maskv);
        __syncthreads();                           // drains vmcnt -> chunk ready

        unsigned short* Pw = Ps[w];
#pragma unroll
        for (int i = 0; i < 4; i++) {
            // S-chunk = Q_strip · K_chunk^T  (16 q x 64 k)
            f4v sacc[4];
#pragma unroll
            for (int n = 0; n < 4; n++) sacc[n] = (f4v){0.f, 0.f, 0.f, 0.f};
#pragma unroll
            for (int ks = 0; ks < 2; ks++) {
                int sw = ((ks * 4 + quad) ^ l7) * 8;
#pragma unroll
                for (int n = 0; n < 4; n++) {
                    s8v bk = *(const s8v*)&Kc[(n * 16 + l16) * 64 + sw];
                    sacc[n] = __builtin_amdgcn_mfma_f32_16x16x32_bf16(aq[i][ks], bk, sacc[n], 0, 0, 0);
                }
            }
            // p = exp2(s + msub): scale+ln2 folded into Q; mask pre-scaled
#pragma unroll
            for (int n = 0; n < 4; n++) {
                float msub = maskv[n * 16 + l16] * -1.4426950409e10f;
                int colpart = n * 2 + lh;
#pragma unroll
                for (int r = 0; r < 4; r++) {
                    float p = exp2f(sacc[n][r] + msub);
                    unsigned int u = __float_as_uint(p);
                    psum[i][r] += __uint_as_float(u & 0xffff0000u);
                    Pw[(quad * 4 + r) * 64 + ((colpart ^ (q4 + r)) * 8) + l7] =
                        (unsigned short)(u >> 16);
                }
            }
            // O_strip += P · V_chunk   (wave-private Ps: no barrier needed)
#pragma unroll
            for (int ks = 0; ks < 2; ks++) {
                int sw = ((ks * 4 + quad) ^ l7) * 8;
                s8v ap = *(const s8v*)&Pw[l16 * 64 + sw];
#pragma unroll
                for (int n = 0; n < 4; n++) {
                    s8v bv = *(const s8v*)&Vc[(n * 16 + l16) * 64 + sw];
                    acc[i][n] = __builtin_amdgcn_mfma_f32_16x16x32_bf16(ap, bv, acc[i][n], 0, 0, 0);
                }
            }
        }
    }

    // deferred normalization + store
#pragma unroll
    for (int i = 0; i < 4; i++) {
        float inv[4];
#pragma unroll
        for (int r = 0; r < 4; r++) {
            float s = psum[i][r];
#pragma unroll
            for (int off = 1; off < 16; off <<= 1) s += __shfl_xor(s, off, 64);
            inv[r] = 1.0f / s;
        }
#pragma unroll
        for (int n = 0; n < 4; n++)
#pragma unroll
            for (int r = 0; r < 4; r++) {
                int query = (w * 4 + i) * 16 + quad * 4 + r;
                int col = h * 64 + n * 16 + l16;
                attn[(size_t)(b * Sn + query) * (Hn * Dn) + col] = f2bf(acc[i][n][r] * inv[r]);
            }
    }
}

// ---------------------------------------------------------------- outproj
// out[32768,512] = attn[32768,512] x WOt^T, fp32 out. grid (4 nb, 256 mb).
__global__ __launch_bounds__(256) void outproj(const unsigned short* __restrict__ attn,
                                               const unsigned short* __restrict__ WOt,
                                               float* __restrict__ out) {
    int nb = blockIdx.x, mb = blockIdx.y;
    __shared__ __align__(16) unsigned short At[128 * 64];
    __shared__ __align__(16) unsigned short Bt[128 * 64];
    int tid = threadIdx.x;
    int w = tid >> 6, lane = tid & 63, quad = lane >> 4, l16 = lane & 15;
    int wr = w >> 1, wc = w & 1;
    int lrow = lane >> 3;
    int lseg = ((lane & 7) ^ lrow) * 8;

    f4v acc[4][4];
#pragma unroll
    for (int i = 0; i < 4; i++)
#pragma unroll
        for (int n = 0; n < 4; n++) acc[i][n] = (f4v){0.f, 0.f, 0.f, 0.f};

    const unsigned short* Ag = attn + (size_t)mb * 128 * 512;
    const unsigned short* Bg = WOt + (size_t)nb * 128 * 512;

    for (int kc = 0; kc < 8; kc++) {
        __syncthreads();
#pragma unroll
        for (int i = 0; i < 4; i++) {
            int r0 = w * 32 + i * 8;
            async16(Ag + (r0 + lrow) * 512 + kc * 64 + lseg, &At[r0 * 64]);
            async16(Bg + (r0 + lrow) * 512 + kc * 64 + lseg, &Bt[r0 * 64]);
        }
        __syncthreads();
#pragma unroll
        for (int ks = 0; ks < 2; ks++) {
            int sw = ((ks * 4 + quad) ^ (l16 & 7)) * 8;
            s8v a[4], b[4];
#pragma unroll
            for (int i = 0; i < 4; i++)
                a[i] = *(const s8v*)&At[(wr * 64 + i * 16 + l16) * 64 + sw];
#pragma unroll
            for (int n = 0; n < 4; n++)
                b[n] = *(const s8v*)&Bt[(wc * 64 + n * 16 + l16) * 64 + sw];
#pragma unroll
            for (int i = 0; i < 4; i++)
#pragma unroll
                for (int n = 0; n < 4; n++)
                    acc[i][n] = __builtin_amdgcn_mfma_f32_16x16x32_bf16(a[i], b[n], acc[i][n], 0, 0, 0);
        }
    }
#pragma unroll
    for (int i = 0; i < 4; i++)
#pragma unroll
        for (int n = 0; n < 4; n++)
#pragma unroll
            for (int r = 0; r < 4; r++) {
                int row = mb * 128 + wr * 64 + i * 16 + quad * 4 + r;
                int col = nb * 128 + wc * 64 + n * 16 + l16;
                out[(size_t)row * 512 + col] = acc[i][n][r];
            }
}

// ---------------------------------------------------------------- launch
extern "C" void kernel_launch(void* const* d_in, const int* in_sizes, int n_in,
                              void* d_out, int out_size, void* d_ws, size_t ws_size,
                              hipStream_t stream) {
    const float* x    = (const float*)d_in[0];
    const float* mask = (const float*)d_in[1];
    const float* WQ   = (const float*)d_in[2];
    const float* WK   = (const float*)d_in[3];
    const float* WV   = (const float*)d_in[4];
    const float* BE   = (const float*)d_in[5];
    const float* WO   = (const float*)d_in[6];
    float* out = (float*)d_out;

    char* ws = (char*)d_ws;
    unsigned short* hbf   = (unsigned short*)(ws);                 // 33554432 B
    unsigned short* Wqkvt = (unsigned short*)(ws + 33554432);      //  1572864 B
    unsigned short* WOt   = (unsigned short*)(ws + 35127296);      //   524288 B
    unsigned short* Qp    = (unsigned short*)(ws + 35651584);      // 33554432 B
    unsigned short* Kp    = (unsigned short*)(ws + 69206016);      // 33554432 B
    unsigned short* Vtp   = (unsigned short*)(ws + 102760448);     // 33554432 B
    unsigned short* attnp = (unsigned short*)(ws + 136314880);     // 33554432 B

    prep_h<<<16384, 256, 0, stream>>>(x, BE, hbf);
    prep_w<<<4096, 256, 0, stream>>>(WQ, WK, WV, WO, Wqkvt, WOt);
    qkv_gemm<<<dim3(12, 256), 256, 0, stream>>>(hbf, Wqkvt, Qp, Kp, Vtp);
    attn_kernel<<<Bn * Hn, 512, 0, stream>>>(Qp, Kp, Vtp, mask, attnp);
    outproj<<<dim3(4, 256), 256, 0, stream>>>(attnp, WOt, out);
}

// Round 6
// 296.287 us; speedup vs baseline: 1.1061x; 1.1061x over previous
//
#include <hip/hip_runtime.h>
#include <hip/hip_bf16.h>

// SelfAttentionLayer: B=64 S=512 E=512 H=8 D=64
// Round 6: S^T-form attention (keys along C-rows) -> vectorized P pack
// (b64 writes), strip-shared frag reads, raw v_exp_f32, 2 blocks/(b,h).
// qkv_gemm / outproj / preps unchanged from round 2/3 (verified passing).

#define Bn 64
#define Sn 512
#define En 512
#define Hn 8
#define Dn 64

typedef __attribute__((ext_vector_type(8))) short s8v;   // 8 bf16 = 4 VGPRs
typedef __attribute__((ext_vector_type(4))) float f4v;   // 4 fp32 acc

__device__ __forceinline__ unsigned short f2bf(float f) {
    union { float f; unsigned int u; } v; v.f = f;
    unsigned int u = v.u;
    u += 0x7fffu + ((u >> 16) & 1u);   // round-to-nearest-even
    return (unsigned short)(u >> 16);
}

__device__ __forceinline__ void async16(const unsigned short* g, unsigned short* l) {
    __builtin_amdgcn_global_load_lds((const __attribute__((address_space(1))) void*)g,
                                     (__attribute__((address_space(3))) void*)l, 16, 0, 0);
}
__device__ __forceinline__ void async4(const float* g, float* l) {
    __builtin_amdgcn_global_load_lds((const __attribute__((address_space(1))) void*)g,
                                     (__attribute__((address_space(3))) void*)l, 4, 0, 0);
}

// ---------------------------------------------------------------- prep_h
__global__ __launch_bounds__(256) void prep_h(const float* __restrict__ x,
                                              const float* __restrict__ BE,
                                              unsigned short* __restrict__ hbf) {
    int i = (blockIdx.x * 256 + threadIdx.x) * 4;
    int se = i % (Sn * En);
    float4 a = *(const float4*)(x + i);
    float4 b = *(const float4*)(BE + se);
    ushort4 o;
    o.x = f2bf(a.x + b.x); o.y = f2bf(a.y + b.y);
    o.z = f2bf(a.z + b.z); o.w = f2bf(a.w + b.w);
    *(ushort4*)(hbf + i) = o;
}

// ---------------------------------------------------------------- prep_w
__global__ __launch_bounds__(256) void prep_w(const float* __restrict__ WQ,
                                              const float* __restrict__ WK,
                                              const float* __restrict__ WV,
                                              const float* __restrict__ WO,
                                              unsigned short* __restrict__ Wqkvt,
                                              unsigned short* __restrict__ WOt) {
    int idx = blockIdx.x * 256 + threadIdx.x;
    const int NW = 3 * Hn * Dn * En;                   // 786432
    if (idx < NW) {
        int e = idx & 511;
        int d = (idx >> 9) & 63;
        int h = (idx >> 15) & 7;
        int m = idx >> 18;
        const float* W = (m == 0) ? WQ : (m == 1) ? WK : WV;
        Wqkvt[idx] = f2bf(W[(h * En + e) * Dn + d]);   // [m][h][d][e]
    } else {
        int j = idx - NW;
        int n = j & 511;
        int e = j >> 9;
        WOt[j] = f2bf(WO[n * En + e]);                  // WO_t[e][hd]
    }
}

// ---------------------------------------------------------------- qkv_gemm
// C[32768,1536] = hbf[32768,512] x Wqkvt^T. grid (12 nb, 256 mb), 256 thr.
__global__ __launch_bounds__(256) void qkv_gemm(const unsigned short* __restrict__ hbf,
                                                const unsigned short* __restrict__ Wqkvt,
                                                unsigned short* __restrict__ Qo,
                                                unsigned short* __restrict__ Ko,
                                                unsigned short* __restrict__ Vt) {
    int nb = blockIdx.x, mb = blockIdx.y;
    __shared__ __align__(16) unsigned short At[128 * 64];
    __shared__ __align__(16) unsigned short Bt[128 * 64];
    int tid = threadIdx.x;
    int w = tid >> 6, lane = tid & 63, quad = lane >> 4, l16 = lane & 15;
    int wr = w >> 1, wc = w & 1;
    int lrow = lane >> 3;
    int lseg = ((lane & 7) ^ lrow) * 8;

    f4v acc[4][4];
#pragma unroll
    for (int i = 0; i < 4; i++)
#pragma unroll
        for (int n = 0; n < 4; n++) acc[i][n] = (f4v){0.f, 0.f, 0.f, 0.f};

    const unsigned short* Ag = hbf + (size_t)mb * 128 * 512;
    const unsigned short* Bg = Wqkvt + (size_t)nb * 128 * 512;

    for (int kc = 0; kc < 8; kc++) {
        __syncthreads();
#pragma unroll
        for (int i = 0; i < 4; i++) {
            int r0 = w * 32 + i * 8;
            async16(Ag + (r0 + lrow) * 512 + kc * 64 + lseg, &At[r0 * 64]);
            async16(Bg + (r0 + lrow) * 512 + kc * 64 + lseg, &Bt[r0 * 64]);
        }
        __syncthreads();
#pragma unroll
        for (int ks = 0; ks < 2; ks++) {
            int sw = ((ks * 4 + quad) ^ (l16 & 7)) * 8;
            s8v a[4], b[4];
#pragma unroll
            for (int i = 0; i < 4; i++)
                a[i] = *(const s8v*)&At[(wr * 64 + i * 16 + l16) * 64 + sw];
#pragma unroll
            for (int n = 0; n < 4; n++)
                b[n] = *(const s8v*)&Bt[(wc * 64 + n * 16 + l16) * 64 + sw];
#pragma unroll
            for (int i = 0; i < 4; i++)
#pragma unroll
                for (int n = 0; n < 4; n++)
                    acc[i][n] = __builtin_amdgcn_mfma_f32_16x16x32_bf16(a[i], b[n], acc[i][n], 0, 0, 0);
        }
    }

    int mat = nb >> 2;
    int h = (nb & 3) * 2 + wc;
    int b = mb >> 2;
    int s0 = (mb & 3) * 128 + wr * 64;
    const float qscale = 0.06375873f;   // log2(e)/sqrt(512): scale + exp->exp2 fold

    if (mat < 2) {
        unsigned short* op = (mat == 0) ? Qo : Ko;
        float sc = (mat == 0) ? qscale : 1.0f;
#pragma unroll
        for (int i = 0; i < 4; i++)
#pragma unroll
            for (int n = 0; n < 4; n++)
#pragma unroll
                for (int r = 0; r < 4; r++) {
                    int s = s0 + i * 16 + quad * 4 + r;
                    int d = n * 16 + l16;
                    op[(size_t)((b * Hn + h) * Sn + s) * Dn + d] = f2bf(acc[i][n][r] * sc);
                }
    } else {
        // V transposed: Vt[b][h][d][s]
#pragma unroll
        for (int i = 0; i < 4; i++)
#pragma unroll
            for (int n = 0; n < 4; n++) {
                int d = n * 16 + l16;
                int s = s0 + i * 16 + quad * 4;
                ushort4 pk;
                pk.x = f2bf(acc[i][n][0]); pk.y = f2bf(acc[i][n][1]);
                pk.z = f2bf(acc[i][n][2]); pk.w = f2bf(acc[i][n][3]);
                *(ushort4*)&Vt[(size_t)((b * Hn + h) * Dn + d) * Sn + s] = pk;
            }
    }
}

// ---------------------------------------------------------------- attention
// grid (2 qhalf, 512 bh), 256 thr (4 waves). Wave w owns strips i=0..3
// (16 queries each of this block's 256-query half). S^T form:
//   sacc = mfma(A=K_frag, B=Q_frag): C rows = keys (key = n*16+quad*4+r),
//   col = query l16.
//   -> P packed uint2 -> b64 LDS writes, logical [query][key] swizzled
//   -> PV: A=P (b128), B=V^T rows; C rows = queries, cols = d.
__global__ __launch_bounds__(256) void attn_kernel(const unsigned short* __restrict__ Q,
                                                   const unsigned short* __restrict__ K,
                                                   const unsigned short* __restrict__ Vt,
                                                   const float* __restrict__ mask,
                                                   unsigned short* __restrict__ attn) {
    int qhalf = blockIdx.x, bh = blockIdx.y;
    int h = bh & 7, b = bh >> 3;
    __shared__ __align__(16) unsigned short Kc[64 * 64];        // [key][d] swizzled
    __shared__ __align__(16) unsigned short Vc[64 * 64];        // [d][key] swizzled
    __shared__ __align__(16) unsigned short Ps[4][4 * 16 * 64]; // [wave][strip][q][key]
    __shared__ float maskv[64];
    int tid = threadIdx.x;
    int w = tid >> 6, lane = tid & 63, quad = lane >> 4, l16 = lane & 15;
    int l7 = l16 & 7;

    const unsigned short* Qg = Q + (size_t)(bh * Sn + qhalf * 256) * Dn;
    const unsigned short* Kg = K + (size_t)(bh * Sn) * Dn;
    const unsigned short* Vg = Vt + (size_t)(bh * Dn) * Sn;

    // Q frags (A/B lane layouts identical), registers, whole kernel
    s8v aq[4][2];
#pragma unroll
    for (int i = 0; i < 4; i++)
#pragma unroll
        for (int ks = 0; ks < 2; ks++)
            aq[i][ks] = *(const s8v*)&Qg[((w * 4 + i) * 16 + l16) * 64 + ks * 32 + quad * 8];

    f4v acc[4][4];
    float psum[4] = {0.f, 0.f, 0.f, 0.f};
#pragma unroll
    for (int i = 0; i < 4; i++)
#pragma unroll
        for (int n = 0; n < 4; n++) acc[i][n] = (f4v){0.f, 0.f, 0.f, 0.f};

    // staging: each async16 covers 8 rows (64 lanes x 16B); wave w rows w*16..+15
    int srow0 = w * 16 + (lane >> 3);
    int srow1 = srow0 + 8;
    int gseg0 = ((lane & 7) ^ (srow0 & 7)) * 8;   // global seg so LDS[p] = g ^ (row&7)
    int gseg1 = ((lane & 7) ^ (srow1 & 7)) * 8;
    unsigned short* kdst0 = &Kc[(w * 16) * 64];
    unsigned short* kdst1 = &Kc[(w * 16 + 8) * 64];
    unsigned short* vdst0 = &Vc[(w * 16) * 64];
    unsigned short* vdst1 = &Vc[(w * 16 + 8) * 64];

    unsigned short* Pw = Ps[w];
    int wbase = l16 * 64 + (quad & 1) * 4;        // P write: row l16 + sub-offset
    const float cM = -1.4426950409e10f;           // -1e10 * log2(e)

    for (int kc = 0; kc < 8; kc++) {
        __syncthreads();                          // all waves done with prev chunk
        async16(Kg + (kc * 64 + srow0) * 64 + gseg0, kdst0);
        async16(Kg + (kc * 64 + srow1) * 64 + gseg1, kdst1);
        async16(Vg + srow0 * 512 + kc * 64 + gseg0, vdst0);
        async16(Vg + srow1 * 512 + kc * 64 + gseg1, vdst1);
        if (w == 0) async4(mask + b * Sn + kc * 64 + lane, maskv);
        __syncthreads();                          // vmcnt drained -> chunk ready

        // ---- S^T = K Q^T per key-tile n; bk shared across all 4 strips ----
#pragma unroll
        for (int n = 0; n < 4; n++) {
            s8v bk0 = *(const s8v*)&Kc[(n * 16 + l16) * 64 + (quad ^ l7) * 8];
            s8v bk1 = *(const s8v*)&Kc[(n * 16 + l16) * 64 + ((4 + quad) ^ l7) * 8];
            float4 mv = *(const float4*)&maskv[n * 16 + quad * 4];
            float m0 = mv.x * cM, m1 = mv.y * cM, m2 = mv.z * cM, m3 = mv.w * cM;
            int wseg = ((n * 2 + (quad >> 1)) ^ l7) * 8;
            f4v sacc[4];
#pragma unroll
            for (int i = 0; i < 4; i++) {
                sacc[i] = __builtin_amdgcn_mfma_f32_16x16x32_bf16(
                              bk0, aq[i][0], (f4v){0.f, 0.f, 0.f, 0.f}, 0, 0, 0);
                sacc[i] = __builtin_amdgcn_mfma_f32_16x16x32_bf16(
                              bk1, aq[i][1], sacc[i], 0, 0, 0);
            }
#pragma unroll
            for (int i = 0; i < 4; i++) {
                unsigned int u0 = __float_as_uint(__builtin_amdgcn_exp2f(sacc[i][0] + m0));
                unsigned int u1 = __float_as_uint(__builtin_amdgcn_exp2f(sacc[i][1] + m1));
                unsigned int u2 = __float_as_uint(__builtin_amdgcn_exp2f(sacc[i][2] + m2));
                unsigned int u3 = __float_as_uint(__builtin_amdgcn_exp2f(sacc[i][3] + m3));
                psum[i] += __uint_as_float(u0 & 0xffff0000u) + __uint_as_float(u1 & 0xffff0000u)
                         + __uint_as_float(u2 & 0xffff0000u) + __uint_as_float(u3 & 0xffff0000u);
                uint2 pk;
                pk.x = (u0 >> 16) | (u1 & 0xffff0000u);
                pk.y = (u2 >> 16) | (u3 & 0xffff0000u);
                *(uint2*)&Pw[(i << 10) + wbase + wseg] = pk;
            }
        }
        // Ps is wave-private; DS ops in-order per wave -> no barrier needed.

        // ---- O += P V : ks-outer, ap/bv shared across strips ----
#pragma unroll
        for (int ks = 0; ks < 2; ks++) {
            int sw = ((ks * 4 + quad) ^ l7) * 8;
            s8v ap[4];
#pragma unroll
            for (int i = 0; i < 4; i++)
                ap[i] = *(const s8v*)&Pw[(i << 10) + l16 * 64 + sw];
#pragma unroll
            for (int n = 0; n < 4; n++) {
                s8v bv = *(const s8v*)&Vc[(n * 16 + l16) * 64 + sw];
#pragma unroll
                for (int i = 0; i < 4; i++)
                    acc[i][n] = __builtin_amdgcn_mfma_f32_16x16x32_bf16(ap[i], bv, acc[i][n], 0, 0, 0);
            }
        }
    }

    // deferred normalization: psum[i] is quad-partial for query l16
#pragma unroll
    for (int i = 0; i < 4; i++) {
        float s = psum[i];
        s += __shfl_xor(s, 16, 64);
        s += __shfl_xor(s, 32, 64);               // every lane: total for query l16
        float inv[4];
#pragma unroll
        for (int r = 0; r < 4; r++)
            inv[r] = 1.0f / __shfl(s, quad * 4 + r, 64);
#pragma unroll
        for (int n = 0; n < 4; n++)
#pragma unroll
            for (int r = 0; r < 4; r++) {
                int query = qhalf * 256 + (w * 4 + i) * 16 + quad * 4 + r;
                int col = h * 64 + n * 16 + l16;
                attn[(size_t)(b * Sn + query) * (Hn * Dn) + col] = f2bf(acc[i][n][r] * inv[r]);
            }
    }
}

// ---------------------------------------------------------------- outproj
// out[32768,512] = attn[32768,512] x WOt^T, fp32 out. grid (4 nb, 256 mb).
__global__ __launch_bounds__(256) void outproj(const unsigned short* __restrict__ attn,
                                               const unsigned short* __restrict__ WOt,
                                               float* __restrict__ out) {
    int nb = blockIdx.x, mb = blockIdx.y;
    __shared__ __align__(16) unsigned short At[128 * 64];
    __shared__ __align__(16) unsigned short Bt[128 * 64];
    int tid = threadIdx.x;
    int w = tid >> 6, lane = tid & 63, quad = lane >> 4, l16 = lane & 15;
    int wr = w >> 1, wc = w & 1;
    int lrow = lane >> 3;
    int lseg = ((lane & 7) ^ lrow) * 8;

    f4v acc[4][4];
#pragma unroll
    for (int i = 0; i < 4; i++)
#pragma unroll
        for (int n = 0; n < 4; n++) acc[i][n] = (f4v){0.f, 0.f, 0.f, 0.f};

    const unsigned short* Ag = attn + (size_t)mb * 128 * 512;
    const unsigned short* Bg = WOt + (size_t)nb * 128 * 512;

    for (int kc = 0; kc < 8; kc++) {
        __syncthreads();
#pragma unroll
        for (int i = 0; i < 4; i++) {
            int r0 = w * 32 + i * 8;
            async16(Ag + (r0 + lrow) * 512 + kc * 64 + lseg, &At[r0 * 64]);
            async16(Bg + (r0 + lrow) * 512 + kc * 64 + lseg, &Bt[r0 * 64]);
        }
        __syncthreads();
#pragma unroll
        for (int ks = 0; ks < 2; ks++) {
            int sw = ((ks * 4 + quad) ^ (l16 & 7)) * 8;
            s8v a[4], b[4];
#pragma unroll
            for (int i = 0; i < 4; i++)
                a[i] = *(const s8v*)&At[(wr * 64 + i * 16 + l16) * 64 + sw];
#pragma unroll
            for (int n = 0; n < 4; n++)
                b[n] = *(const s8v*)&Bt[(wc * 64 + n * 16 + l16) * 64 + sw];
#pragma unroll
            for (int i = 0; i < 4; i++)
#pragma unroll
                for (int n = 0; n < 4; n++)
                    acc[i][n] = __builtin_amdgcn_mfma_f32_16x16x32_bf16(a[i], b[n], acc[i][n], 0, 0, 0);
        }
    }
#pragma unroll
    for (int i = 0; i < 4; i++)
#pragma unroll
        for (int n = 0; n < 4; n++)
#pragma unroll
            for (int r = 0; r < 4; r++) {
                int row = mb * 128 + wr * 64 + i * 16 + quad * 4 + r;
                int col = nb * 128 + wc * 64 + n * 16 + l16;
                out[(size_t)row * 512 + col] = acc[i][n][r];
            }
}

// ---------------------------------------------------------------- launch
extern "C" void kernel_launch(void* const* d_in, const int* in_sizes, int n_in,
                              void* d_out, int out_size, void* d_ws, size_t ws_size,
                              hipStream_t stream) {
    const float* x    = (const float*)d_in[0];
    const float* mask = (const float*)d_in[1];
    const float* WQ   = (const float*)d_in[2];
    const float* WK   = (const float*)d_in[3];
    const float* WV   = (const float*)d_in[4];
    const float* BE   = (const float*)d_in[5];
    const float* WO   = (const float*)d_in[6];
    float* out = (float*)d_out;

    char* ws = (char*)d_ws;
    unsigned short* hbf   = (unsigned short*)(ws);                 // 33554432 B
    unsigned short* Wqkvt = (unsigned short*)(ws + 33554432);      //  1572864 B
    unsigned short* WOt   = (unsigned short*)(ws + 35127296);      //   524288 B
    unsigned short* Qp    = (unsigned short*)(ws + 35651584);      // 33554432 B
    unsigned short* Kp    = (unsigned short*)(ws + 69206016);      // 33554432 B
    unsigned short* Vtp   = (unsigned short*)(ws + 102760448);     // 33554432 B
    unsigned short* attnp = (unsigned short*)(ws + 136314880);     // 33554432 B

    prep_h<<<16384, 256, 0, stream>>>(x, BE, hbf);
    prep_w<<<4096, 256, 0, stream>>>(WQ, WK, WV, WO, Wqkvt, WOt);
    qkv_gemm<<<dim3(12, 256), 256, 0, stream>>>(hbf, Wqkvt, Qp, Kp, Vtp);
    attn_kernel<<<dim3(2, 512), 256, 0, stream>>>(Qp, Kp, Vtp, mask, attnp);
    outproj<<<dim3(4, 256), 256, 0, stream>>>(attnp, WOt, out);
}